// Round 18
// baseline (720.125 us; speedup 1.0000x reference)
//
#include <hip/hip_runtime.h>
#include <hip/hip_bf16.h>
#include <stdint.h>

typedef __bf16 bf16_t;
typedef bf16_t bf16x8 __attribute__((ext_vector_type(8)));
typedef float f32x4 __attribute__((ext_vector_type(4)));
typedef uint16_t u16x8 __attribute__((ext_vector_type(8)));

static constexpr int B_TOK  = 4096;
static constexpr int E_DIM  = 1024;
static constexpr int N_EXPC = 8;
static constexpr int HID    = 4096;
static constexpr int IMGSZ  = 4096;
static constexpr int NSLOT  = 2 * B_TOK;
static constexpr int NTIL   = 71;          // max 128-row tiles: 64 + 7 remainder tiles

#define DEVI __device__ __forceinline__

DEVI int imin(int a, int b) { return a < b ? a : b; }

DEVI uint16_t f2bf(float f) {
  union { float f; uint32_t u; } v; v.f = f;
  uint32_t u = v.u;
  return (uint16_t)((u + 0x7FFFu + ((u >> 16) & 1u)) >> 16);
}

DEVI float bf2f(uint16_t u) {
  union { uint32_t i; float f; } v; v.i = (uint32_t)u << 16; return v.f;
}

DEVI void gload_lds16(const void* g, void* l) {
  __builtin_amdgcn_global_load_lds((const __attribute__((address_space(1))) void*)g,
                                   (__attribute__((address_space(3))) void*)l, 16, 0, 0);
}

template<int N> DEVI void waitv() {
  if constexpr (N == 0)       asm volatile("s_waitcnt vmcnt(0)" ::: "memory");
  else if constexpr (N == 4)  asm volatile("s_waitcnt vmcnt(4)" ::: "memory");
  else if constexpr (N == 8)  asm volatile("s_waitcnt vmcnt(8)" ::: "memory");
  else if constexpr (N == 10) asm volatile("s_waitcnt vmcnt(10)" ::: "memory");
}

#define BAR() do { __builtin_amdgcn_sched_barrier(0); __builtin_amdgcn_s_barrier(); \
                   __builtin_amdgcn_sched_barrier(0); } while (0)

#define MFMA16(a, b, c) __builtin_amdgcn_mfma_f32_16x16x32_bf16((a), (b), (c), 0, 0, 0)

// ---------------- device helpers reused across merged kernels ----------------
DEVI void transW_body(int bid, const float* W1, const float* W2,
                      const float* We, const float* Wi,
                      uint16_t* W1T, uint16_t* W2T, uint16_t* WeT, uint16_t* WiT,
                      float (*tile)[65])
{
  const float* in; uint16_t* out; int R, C, c0, r0;
  if (bid < 8192) {                       // W1: 8 x [1024][4096]
    int e = bid >> 10, rem = bid & 1023;
    R = 1024; C = 4096;
    c0 = (rem & 63) * 64; r0 = (rem >> 6) * 64;
    in = W1 + (size_t)e * R * C; out = W1T + (size_t)e * R * C;
  } else if (bid < 16384) {               // W2: 8 x [4096][1024]
    int i = bid - 8192; int e = i >> 10, rem = i & 1023;
    R = 4096; C = 1024;
    c0 = (rem & 15) * 64; r0 = (rem >> 4) * 64;
    in = W2 + (size_t)e * R * C; out = W2T + (size_t)e * R * C;
  } else if (bid < 16640) {               // W_enc: [4096][256]
    int i = bid - 16384;
    R = 4096; C = 256;
    c0 = (i & 3) * 64; r0 = (i >> 2) * 64;
    in = We; out = WeT;
  } else {                                // W_img: [1024][256]
    int i = bid - 16640;
    R = 1024; C = 256;
    c0 = (i & 3) * 64; r0 = (i >> 2) * 64;
    in = Wi; out = WiT;
  }
  int t = threadIdx.x;
  #pragma unroll
  for (int i = 0; i < 4; ++i) {
    int rr = i * 16 + (t >> 4), c4 = (t & 15) * 4;
    f32x4 v = *(const f32x4*)&in[(size_t)(r0 + rr) * C + c0 + c4];
    tile[rr][c4 + 0] = v[0]; tile[rr][c4 + 1] = v[1];
    tile[rr][c4 + 2] = v[2]; tile[rr][c4 + 3] = v[3];
  }
  __syncthreads();
  #pragma unroll
  for (int i = 0; i < 2; ++i) {
    int c = i * 32 + (t >> 3), j = t & 7;
    u16x8 o;
    #pragma unroll
    for (int k = 0; k < 8; ++k) o[k] = f2bf(tile[j * 8 + k][c]);
    *(u16x8*)&out[(size_t)(c0 + c) * R + r0 + j * 8] = o;
  }
}

// out[k][e] = sum_m W[k][m] * G[m][e]   (wave per k-row; 4 rows/block)
DEVI void matf_body(int kblk, const float* W, const float* G, float* out)
{
  int k = kblk * 4 + (threadIdx.x >> 6);
  int lane = threadIdx.x & 63;
  float a0 = 0.f, a1 = 0.f, a2 = 0.f, a3 = 0.f, a4 = 0.f, a5 = 0.f, a6 = 0.f, a7 = 0.f;
  for (int m = lane; m < E_DIM; m += 64) {
    float w = W[(size_t)k * E_DIM + m];
    const float* gm = &G[m * 8];
    a0 = __builtin_fmaf(w, gm[0], a0); a1 = __builtin_fmaf(w, gm[1], a1);
    a2 = __builtin_fmaf(w, gm[2], a2); a3 = __builtin_fmaf(w, gm[3], a3);
    a4 = __builtin_fmaf(w, gm[4], a4); a5 = __builtin_fmaf(w, gm[5], a5);
    a6 = __builtin_fmaf(w, gm[6], a6); a7 = __builtin_fmaf(w, gm[7], a7);
  }
  #pragma unroll
  for (int off = 32; off; off >>= 1) {
    a0 += __shfl_xor(a0, off); a1 += __shfl_xor(a1, off);
    a2 += __shfl_xor(a2, off); a3 += __shfl_xor(a3, off);
    a4 += __shfl_xor(a4, off); a5 += __shfl_xor(a5, off);
    a6 += __shfl_xor(a6, off); a7 += __shfl_xor(a7, off);
  }
  if (lane == 0) {
    float* o = &out[k * 8];
    o[0] = a0; o[1] = a1; o[2] = a2; o[3] = a3;
    o[4] = a4; o[5] = a5; o[6] = a6; o[7] = a7;
  }
}

// ---------------- D1: transW || matf1(Wo@Wg) || bvwo || zero ----------------
__global__ __launch_bounds__(256)
void prep1_k(const float* __restrict__ W1, const float* __restrict__ W2,
             const float* __restrict__ We, const float* __restrict__ Wi,
             uint16_t* __restrict__ W1T, uint16_t* __restrict__ W2T,
             uint16_t* __restrict__ WeT, uint16_t* __restrict__ WiT,
             const float* __restrict__ Wo, const float* __restrict__ Wg,
             float* __restrict__ g1c,
             const float* __restrict__ bv, float* __restrict__ part,
             int* __restrict__ counts)
{
  __shared__ float tile[64][65];
  int bid = blockIdx.x;
  if (bid < 16704) {
    transW_body(bid, W1, W2, We, Wi, W1T, W2T, WeT, WiT, tile);
  } else if (bid < 16960) {
    matf_body(bid - 16704, Wo, Wg, g1c);
  } else if (bid < 16968) {
    int b = bid - 16960, t = threadIdx.x;
    f32x4 acc = {0.f, 0.f, 0.f, 0.f};
    for (int k = b * 128; k < b * 128 + 128; ++k) {
      float s = bv[k];
      f32x4 w = *(const f32x4*)&Wo[(size_t)k * E_DIM + t * 4];
      acc[0] = __builtin_fmaf(s, w[0], acc[0]);
      acc[1] = __builtin_fmaf(s, w[1], acc[1]);
      acc[2] = __builtin_fmaf(s, w[2], acc[2]);
      acc[3] = __builtin_fmaf(s, w[3], acc[3]);
    }
    *(f32x4*)&part[(size_t)b * E_DIM + t * 4] = acc;
  } else {
    if (threadIdx.x < 8) counts[threadIdx.x] = 0;
  }
}

// ---------------- D2: matf2(Wv@g1) || fused t1+gbias ----------------
__global__ __launch_bounds__(256)
void prep2_k(const float* __restrict__ Wv, const float* __restrict__ g1c,
             float* __restrict__ G3,
             const float* __restrict__ part, const float* __restrict__ bo,
             const float* __restrict__ Wg, const float* __restrict__ bg,
             float* __restrict__ gb)
{
  int bid = blockIdx.x;
  if (bid < 256) {
    matf_body(bid, Wv, g1c, G3);
  } else {
    __shared__ float t1s[E_DIM];
    int t = threadIdx.x;
    for (int j = t; j < E_DIM; j += 256) {
      float s = bo[j];
      #pragma unroll
      for (int b = 0; b < 8; ++b) s += part[(size_t)b * E_DIM + j];
      t1s[j] = s;
    }
    __syncthreads();
    int wave = t >> 6, lane = t & 63;
    #pragma unroll
    for (int ei = 0; ei < 2; ++ei) {
      int e = wave * 2 + ei;
      float s = 0.f;
      for (int m = lane; m < E_DIM; m += 64) s = __builtin_fmaf(t1s[m], Wg[m * 8 + e], s);
      #pragma unroll
      for (int off = 32; off; off >>= 1) s += __shfl_xor(s, off);
      if (lane == 0) gb[e] = s + bg[e];
    }
  }
}

// ================= D3 merged: enc/img GEMM (896 blocks, no-LDS streaming) || gate =================
// bid<896: encR z=bid>>7, y=(bid>>6)&1, x=bid&63; both MFMA operands stream global->reg
//   (A f32 fragment: row=l&15, k=(l>>4)*8; B bf16 fragment ditto on BT rows) with a 4-set
//   rolling register pipeline (sets loaded 4 K-steps ahead; all indices compile-time).
//   NO LDS, NO barriers -> latency hidden by ~40 in-flight loads/wave.
// bid>=896: gate token b = bid-896 (logits -> softmax -> top2 -> counts).
__global__ __launch_bounds__(256)
void encgate_k(const float* __restrict__ F0, const float* __restrict__ F1,
               const float* __restrict__ F2, const float* __restrict__ Fimg,
               const uint16_t* __restrict__ BTe, const uint16_t* __restrict__ BTi,
               float* __restrict__ Penc, float* __restrict__ Pimg,
               const float* __restrict__ text, const float* __restrict__ G3,
               const float* __restrict__ gb, float* __restrict__ gate_out,
               int* __restrict__ topIdx, float* __restrict__ topW,
               int* __restrict__ counts)
{
  __shared__ __align__(16) float sT[E_DIM];
  __shared__ float lg[8];
  int bid = blockIdx.x;
  int t = threadIdx.x;

  if (bid >= 896) {                       // ---------------- gate branch ----------------
    int b = bid - 896;
    *(f32x4*)&sT[t * 4] = *(const f32x4*)&text[(size_t)b * E_DIM + t * 4];
    __syncthreads();
    int wave = t >> 6, lane = t & 63;
    #pragma unroll
    for (int ei = 0; ei < 2; ++ei) {
      int e = wave * 2 + ei;
      float s = 0.f;
      for (int k = lane; k < E_DIM; k += 64) s = __builtin_fmaf(sT[k], G3[k * 8 + e], s);
      #pragma unroll
      for (int off = 32; off; off >>= 1) s += __shfl_down(s, off);
      if (lane == 0) lg[e] = s + gb[e];
    }
    __syncthreads();
    if (t == 0) {
      float p[8];
      float mx = lg[0];
      for (int i = 1; i < 8; i++) mx = fmaxf(mx, lg[i]);
      float den = 0.f;
      for (int i = 0; i < 8; i++) { p[i] = __expf(lg[i] - mx); den += p[i]; }
      float inv = 1.f / den;
      for (int i = 0; i < 8; i++) { p[i] *= inv; gate_out[(size_t)b * 8 + i] = p[i]; }
      int i1 = 0;
      for (int i = 1; i < 8; i++) if (p[i] > p[i1]) i1 = i;     // ties -> lower index
      int i2 = (i1 == 0) ? 1 : 0;
      for (int i = 0; i < 8; i++) if (i != i1 && p[i] > p[i2]) i2 = i;
      float ex = __expf(p[i2] - p[i1]);                          // softmax over top-2 probs
      float w1 = 1.f / (1.f + ex), w2 = ex / (1.f + ex);
      topIdx[b * 2] = i1; topIdx[b * 2 + 1] = i2;
      topW[b * 2] = w1;  topW[b * 2 + 1] = w2;
      atomicAdd(&counts[i1], 1);
      atomicAdd(&counts[i2], 1);
    }
    return;
  }

  // ---------------- encR branch: barrier-free dual-stream ----------------
  int z = bid >> 7, yb = (bid >> 6) & 1, xb = bid & 63;
  const float* Af; const uint16_t* BT; float* P; int K, Kc, k0;
  if (z < 6) {
    int br = z >> 1, kc = z & 1;
    Af = (br == 0) ? F0 : (br == 1) ? F1 : F2;
    BT = BTe; P = Penc + (size_t)z * B_TOK * 256;
    K = IMGSZ; Kc = IMGSZ / 2; k0 = kc * Kc;
  } else {
    Af = Fimg; BT = BTi; P = Pimg;
    K = E_DIM; Kc = E_DIM; k0 = 0;
  }
  int rowBase = xb * 64, nt = yb;

  int wave = t >> 6, lane = t & 63;
  int fr = lane & 15, q4 = lane >> 4;

  const float* gA = Af + (size_t)(rowBase + wave * 16 + fr) * K + k0 + q4 * 8;
  const uint16_t* gB[8];
  #pragma unroll
  for (int n = 0; n < 8; ++n)
    gB[n] = BT + (size_t)(nt * 128 + n * 16 + fr) * K + k0 + q4 * 8;

  f32x4 acc[8];
  #pragma unroll
  for (int n = 0; n < 8; ++n) acc[n] = f32x4{0.f, 0.f, 0.f, 0.f};

  int nk = Kc >> 5;                        // 64 (enc) or 32 (img), both %4 == 0

  f32x4 pa[4][2];
  bf16x8 pb[4][8];
  auto LOADSET = [&](int s, int kt) {      // s is a literal at every call site
    int ko = imin(kt, nk - 1) << 5;
    pa[s][0] = *(const f32x4*)(gA + ko);
    pa[s][1] = *(const f32x4*)(gA + ko + 4);
    #pragma unroll
    for (int n = 0; n < 8; ++n) pb[s][n] = *(const bf16x8*)(gB[n] + ko);
  };
  auto COMP = [&](int s) {
    bf16x8 a;
    a[0] = (bf16_t)pa[s][0][0]; a[1] = (bf16_t)pa[s][0][1];
    a[2] = (bf16_t)pa[s][0][2]; a[3] = (bf16_t)pa[s][0][3];
    a[4] = (bf16_t)pa[s][1][0]; a[5] = (bf16_t)pa[s][1][1];
    a[6] = (bf16_t)pa[s][1][2]; a[7] = (bf16_t)pa[s][1][3];
    #pragma unroll
    for (int n = 0; n < 8; ++n) acc[n] = MFMA16(a, pb[s][n], acc[n]);
  };

  LOADSET(0, 0); LOADSET(1, 1); LOADSET(2, 2); LOADSET(3, 3);
  for (int kt = 0; kt < nk; kt += 4) {
    bool more = kt + 4 < nk;
    COMP(0); if (more) LOADSET(0, kt + 4);
    COMP(1); if (more) LOADSET(1, kt + 5);
    COMP(2); if (more) LOADSET(2, kt + 6);
    COMP(3); if (more) LOADSET(3, kt + 7);
  }

  #pragma unroll
  for (int n = 0; n < 8; ++n) {
    int col = nt * 128 + n * 16 + fr;
    #pragma unroll
    for (int r = 0; r < 4; ++r) {
      int row = rowBase + wave * 16 + q4 * 4 + r;
      P[(size_t)row * 256 + col] = acc[n][r];
    }
  }
}

// ================= expert GEMM: round-8 proven 128x128, depth-2 counted-vmcnt =================
// EPI: 1=bias+bf16, 3=gelu(exp-form)->bf16 ; supertile raster + XCD swizzle
template<int BN, int EPI, bool GATHER, int NT>
__global__ __launch_bounds__(256, 3)
void gemm_p(const uint16_t* __restrict__ Ab, int lda,
            const uint16_t* __restrict__ BT, void* __restrict__ Cv, int ldc,
            const float* __restrict__ bias, int K,
            const int* __restrict__ meta, const int* __restrict__ perm,
            size_t bStride, int biasStride)
{
  constexpr int HN = BN / 2, FN = BN / 32;
  constexpr int OPS = (BN == 128 ? 4 : 3);
  constexpr int TOTAL = NTIL * NT, Q = TOTAL / 8, FULLB = 64 * NT;
  int bid = blockIdx.x;
  int wg = (bid & 7) * Q + (bid >> 3);            // XCD swizzle
  int mtile, nt;
  if (wg < FULLB) { int rem = wg % (8 * NT); mtile = (wg / (8 * NT)) * 8 + (rem & 7); nt = rem >> 3; }
  else            { int rem = wg - FULLB;    mtile = 64 + rem % 7;                    nt = rem / 7; }
  if (mtile >= meta[0]) return;
  int e = meta[1 + 3 * mtile], rowBase = meta[2 + 3 * mtile], rows = meta[3 + 3 * mtile];
  const uint16_t* Bt = BT + (size_t)e * bStride;
  const float* bi = bias + (size_t)e * (size_t)biasStride;

  constexpr int ABUF = 8192;
  constexpr int BBUF = (BN == 128) ? 8192 : 4096;
  __shared__ __align__(16) char sAraw[3 * ABUF];
  __shared__ __align__(16) char sBraw[3 * BBUF];

  int t = threadIdx.x, wave = t >> 6, lane = t & 63;
  int wr = wave >> 1, wc = wave & 1;

  int rB = t >> 2;
  int slB = ((t & 3) ^ (rB & 3)) * 8;
  const uint16_t* gB0 = Bt + (size_t)(nt * BN + rB) * K + slB;
  const uint16_t* gB1 = Bt + (size_t)(nt * BN + rB + 64) * K + slB;   // BN==128 only

  int r0 = t >> 2, r1 = r0 + 64;
  int sl = ((t & 3) ^ (r0 & 3)) * 8;
  int rr0 = imin(r0, rows - 1), rr1 = imin(r1, rows - 1);
  int car0 = GATHER ? perm[rowBase + rr0] : rowBase + rr0;
  int car1 = GATHER ? perm[rowBase + rr1] : rowBase + rr1;
  const uint16_t* gA0 = Ab + (size_t)car0 * lda + sl;
  const uint16_t* gA1 = Ab + (size_t)car1 * lda + sl;

  char* laW = sAraw + wave * 1024;
  char* lbW = sBraw + wave * 1024;
  auto STAGE = [&](int kt, int c) {
    int ko = kt << 5;
    char* la = laW + c * ABUF;
    char* lb = lbW + c * BBUF;
    gload_lds16(gA0 + ko, la);
    gload_lds16(gA1 + ko, la + 4096);
    gload_lds16(gB0 + ko, lb);
    if constexpr (BN == 128) gload_lds16(gB1 + ko, lb + 4096);
  };

  f32x4 acc[4][FN];
  #pragma unroll
  for (int m = 0; m < 4; m++)
    #pragma unroll
    for (int n = 0; n < FN; n++)
      acc[m][n] = f32x4{0.f, 0.f, 0.f, 0.f};

  STAGE(0, 0);
  STAGE(1, 1);

  int fr = lane & 15;
  int rdoff = ((lane >> 4) ^ (lane & 3)) * 16;
  int c0 = 0, c2 = 2;
  int nk = K >> 5;

  for (int kt = 0; kt < nk; ++kt) {
    if (kt + 2 < nk) { STAGE(kt + 2, c2); waitv<2 * OPS>(); }
    else if (kt + 1 < nk) waitv<OPS>();
    else waitv<0>();
    BAR();

    const char* bA = sAraw + c0 * ABUF;
    const char* bB = sBraw + c0 * BBUF;
    bf16x8 af[4], bfr[FN];
    #pragma unroll
    for (int m = 0; m < 4; m++)
      af[m] = *(const bf16x8*)(bA + (wr * 64 + m * 16 + fr) * 64 + rdoff);
    #pragma unroll
    for (int n = 0; n < FN; n++)
      bfr[n] = *(const bf16x8*)(bB + (wc * HN + n * 16 + fr) * 64 + rdoff);
    #pragma unroll
    for (int m = 0; m < 4; m++)
      #pragma unroll
      for (int n = 0; n < FN; n++)
        acc[m][n] = MFMA16(af[m], bfr[n], acc[m][n]);

    BAR();
    c0 = (c0 == 2) ? 0 : c0 + 1;
    c2 = (c2 == 2) ? 0 : c2 + 1;
  }

  // epilogue: C/D layout col=lane&15, row=(lane>>4)*4+reg (m89-verified)
  #pragma unroll
  for (int m = 0; m < 4; m++) {
    int lrow = wr * 64 + m * 16 + (lane >> 4) * 4;
    #pragma unroll
    for (int n = 0; n < FN; n++) {
      int col = nt * BN + wc * HN + n * 16 + (lane & 15);
      float bval = bi[col];
      #pragma unroll
      for (int r = 0; r < 4; r++) {
        int lr = lrow + r;
        if (lr >= rows) continue;
        float v = acc[m][n][r] + bval;
        size_t cr = (size_t)(rowBase + lr) * ldc + col;
        if (EPI == 3) {   // gelu(tanh) == v * sigmoid(1.5957691*(v + 0.044715 v^3))
          float u = v + 0.044715f * v * v * v;
          v = v / (1.f + __expf(-1.5957691216057308f * u));
          ((uint16_t*)Cv)[cr] = f2bf(v);
        } else {
          ((uint16_t*)Cv)[cr] = f2bf(v);
        }
      }
    }
  }
}

// merged reduce + post: y<3 -> enc reduce (SK=2), y==3 -> img (SK=1, silu),
// y==4 -> post (x==0: imploss, x==1: scanfill)
__global__ __launch_bounds__(256)
void redupost_k(const float* __restrict__ Penc, const float* __restrict__ Pimg,
                const float* __restrict__ bEnc, const float* __restrict__ bImg,
                uint16_t* __restrict__ xb,
                const float* __restrict__ gate_out, float* __restrict__ out_loss,
                const int* __restrict__ counts, const int* __restrict__ topIdx,
                const float* __restrict__ topW,
                int* __restrict__ meta, int* __restrict__ perm,
                int* __restrict__ slotOf)
{
  int y = blockIdx.y, t = threadIdx.x;
  if (y < 4) {
    int row = blockIdx.x * 4 + (t >> 6);
    int c4 = (t & 63) * 4;
    bool img = (y == 3);
    const float* bias = img ? bImg : bEnc;
    f32x4 s = *(const f32x4*)&bias[c4];
    if (img) {
      s += *(const f32x4*)&Pimg[(size_t)row * 256 + c4];
      #pragma unroll
      for (int j = 0; j < 4; ++j) s[j] = s[j] / (1.f + __expf(-s[j]));
    } else {
      const float* p = Penc + (size_t)y * 2 * B_TOK * 256 + (size_t)row * 256 + c4;
      s += *(const f32x4*)p;
      s += *(const f32x4*)(p + (size_t)B_TOK * 256);
    }
    ushort4 o;
    o.x = f2bf(s[0]); o.y = f2bf(s[1]); o.z = f2bf(s[2]); o.w = f2bf(s[3]);
    *(ushort4*)&xb[(size_t)row * E_DIM + y * 256 + c4] = o;
    return;
  }
  if (blockIdx.x == 0) {                       // imploss
    float s[8] = {0.f, 0.f, 0.f, 0.f, 0.f, 0.f, 0.f, 0.f};
    for (int b = t; b < B_TOK; b += 256) {
      const float* g = &gate_out[(size_t)b * 8];
      #pragma unroll
      for (int e = 0; e < 8; ++e) s[e] += g[e];
    }
    __shared__ float red[8][256];
    #pragma unroll
    for (int e = 0; e < 8; ++e) red[e][t] = s[e];
    __syncthreads();
    for (int off = 128; off; off >>= 1) {
      if (t < off)
        #pragma unroll
        for (int e = 0; e < 8; ++e) red[e][t] += red[e][t + off];
      __syncthreads();
    }
    if (t == 0) {
      float m = 0.f;
      for (int e = 0; e < 8; e++) m += red[e][0];
      m *= 0.125f;
      float v = 0.f;
      for (int e = 0; e < 8; e++) { float d = red[e][0] - m; v += d * d; }
      v /= 7.f;                                  // ddof=1
      out_loss[0] = 0.01f * v / (m * m);
    }
  } else if (blockIdx.x == 1) {                // scanfill
    __shared__ int sBases[8];
    __shared__ int sCursor[8];
    if (t == 0) {
      int a = 0, nt = 0;
      for (int e = 0; e < 8; e++) {
        sBases[e] = a; sCursor[e] = 0;
        int c = counts[e];
        for (int j = 0; j < c; j += 128) {
          meta[1 + 3 * nt] = e;
          meta[2 + 3 * nt] = a + j;
          meta[3 + 3 * nt] = (c - j < 128) ? (c - j) : 128;
          nt++;
        }
        a += c;
      }
      meta[0] = nt;
    }
    __syncthreads();
    for (int b = t; b < B_TOK; b += 256) {
      #pragma unroll
      for (int j = 0; j < 2; j++) {
        int e = topIdx[b * 2 + j];
        int pos = atomicAdd(&sCursor[e], 1);
        int slot = sBases[e] + pos;
        perm[slot] = b;
        slotOf[b * 2 + j] = slot;
      }
    }
  }
}

// weighted top-2 mix from bf16 Yg (bias already added inside expert L2 GEMM)
__global__ __launch_bounds__(256)
void combine_k(const uint16_t* __restrict__ Yg, const int* __restrict__ slotOf,
               const float* __restrict__ topW, float* __restrict__ y)
{
  int b = blockIdx.x, t = threadIdx.x;
  int s0 = slotOf[b * 2], s1 = slotOf[b * 2 + 1];
  float w0 = topW[b * 2], w1 = topW[b * 2 + 1];
  ushort4 ua = *(const ushort4*)&Yg[(size_t)s0 * E_DIM + t * 4];
  ushort4 uc = *(const ushort4*)&Yg[(size_t)s1 * E_DIM + t * 4];
  f32x4 r;
  r[0] = bf2f(ua.x) * w0 + bf2f(uc.x) * w1;
  r[1] = bf2f(ua.y) * w0 + bf2f(uc.y) * w1;
  r[2] = bf2f(ua.z) * w0 + bf2f(uc.z) * w1;
  r[3] = bf2f(ua.w) * w0 + bf2f(uc.w) * w1;
  *(f32x4*)&y[(size_t)b * E_DIM + t * 4] = r;
}

// ---------------- host ----------------
extern "C" void kernel_launch(void* const* d_in, const int* in_sizes, int n_in,
                              void* d_out, int out_size, void* d_ws, size_t ws_size,
                              hipStream_t stream)
{
  (void)in_sizes; (void)n_in; (void)out_size;
  const float* src   = (const float*)d_in[0];
  const float* tgt   = (const float*)d_in[1];
  const float* bgr   = (const float*)d_in[2];
  const float* image = (const float*)d_in[3];
  const float* text  = (const float*)d_in[4];
  const float* W_enc = (const float*)d_in[5];
  const float* b_enc = (const float*)d_in[6];
  const float* W_img = (const float*)d_in[7];
  const float* b_img = (const float*)d_in[8];
  // d_in[9..12]: Wq,bq,Wk,bk — dead (softmax over length-1 key axis == 1)
  const float* Wv    = (const float*)d_in[13];
  const float* bv    = (const float*)d_in[14];
  const float* Wo    = (const float*)d_in[15];
  const float* bo    = (const float*)d_in[16];
  const float* Wg    = (const float*)d_in[17];
  const float* bgg   = (const float*)d_in[18];
  const float* W1    = (const float*)d_in[19];
  const float* b1    = (const float*)d_in[20];
  const float* W2    = (const float*)d_in[21];
  const float* b2    = (const float*)d_in[22];

  float* out_y    = (float*)d_out;
  float* out_gate = out_y + (size_t)B_TOK * E_DIM;
  float* out_loss = out_gate + (size_t)B_TOK * N_EXPC;

  char* p = (char*)d_ws;
  auto alloc = [&](size_t bytes) { char* r = p; p += (bytes + 255) & ~(size_t)255; return r; };
  uint16_t* WencT = (uint16_t*)alloc((size_t)256 * IMGSZ * 2);
  uint16_t* WimgT = (uint16_t*)alloc((size_t)256 * E_DIM * 2);
  uint16_t* W1T   = (uint16_t*)alloc((size_t)N_EXPC * HID * E_DIM * 2);
  uint16_t* W2T   = (uint16_t*)alloc((size_t)N_EXPC * E_DIM * HID * 2);
  float* part  = (float*)alloc((size_t)8 * E_DIM * 4);
  float* g1c   = (float*)alloc((size_t)E_DIM * 8 * 4);
  float* G3    = (float*)alloc((size_t)E_DIM * 8 * 4);
  float* gbv   = (float*)alloc(64 * 4);
  int*   topIdx = (int*)alloc(B_TOK * 2 * 4);
  float* topW   = (float*)alloc(B_TOK * 2 * 4);
  int*   slotOf = (int*)alloc(B_TOK * 2 * 4);
  int*   counts = (int*)alloc(64 * 4);
  int*   meta   = (int*)alloc((1 + 3 * (NTIL + 1)) * 4 + 64);
  int*   perm   = (int*)alloc(NSLOT * 4);
  uint16_t* xbf  = (uint16_t*)alloc((size_t)B_TOK * E_DIM * 2);
  uint16_t* Hbuf = (uint16_t*)alloc((size_t)NSLOT * HID * 2);
  // union region: enc partials (7 planes, 28 MB) then expert output Yg bf16 (16 MB)
  char* uni = alloc((size_t)7 * B_TOK * 256 * 4);
  float* Penc = (float*)uni;                               // 6 planes * 4 MB
  float* Pimg = Penc + (size_t)6 * B_TOK * 256;            // 1 plane
  uint16_t* Yg = (uint16_t*)uni;                           // reused after redupost
  if ((size_t)(p - (char*)d_ws) > ws_size) return;   // ws too small: fail visibly

  // D1: transW || matf1 || bvwo || zero-counts
  prep1_k<<<dim3(16969), 256, 0, stream>>>(W1, W2, W_enc, W_img, W1T, W2T, WencT, WimgT,
                                           Wo, Wg, g1c, bv, part, counts);
  // D2: matf2 || fused t1+gbias
  prep2_k<<<dim3(257), 256, 0, stream>>>(Wv, g1c, G3, part, bo, Wg, bgg, gbv);
  // D3: enc+img GEMMs (896 blocks, barrier-free streaming) || gate (4096 blocks)
  encgate_k<<<dim3(896 + B_TOK), 256, 0, stream>>>(
      src, tgt, bgr, image, WencT, WimgT, Penc, Pimg,
      text, G3, gbv, out_gate, topIdx, topW, counts);
  // D4: merged reduce + post (imploss, scanfill)
  redupost_k<<<dim3(B_TOK / 4, 5), 256, 0, stream>>>(
      Penc, Pimg, b_enc, b_img, xbf,
      out_gate, out_loss, counts, topIdx, topW, meta, perm, slotOf);

  // D5/D6: sparse top-2 expert MLPs (round-8 proven kernels); L2 emits bf16
  gemm_p<128, 3, true, HID / 128><<<dim3(NTIL * (HID / 128)), 256, 0, stream>>>(
      xbf, E_DIM, W1T, Hbuf, HID, b1, E_DIM, meta, perm, (size_t)HID * E_DIM, HID);
  gemm_p<128, 1, false, E_DIM / 128><<<dim3(NTIL * (E_DIM / 128)), 256, 0, stream>>>(
      Hbuf, HID, W2T, Yg, E_DIM, b2, HID, meta, perm, (size_t)E_DIM * HID, E_DIM);

  // D7: combine
  combine_k<<<B_TOK, 256, 0, stream>>>(Yg, slotOf, topW, out_y);
}

// Round 19
// 583.135 us; speedup vs baseline: 1.2349x; 1.2349x over previous
//
#include <hip/hip_runtime.h>
#include <hip/hip_bf16.h>
#include <stdint.h>

typedef __bf16 bf16_t;
typedef bf16_t bf16x8 __attribute__((ext_vector_type(8)));
typedef float f32x4 __attribute__((ext_vector_type(4)));
typedef uint16_t u16x8 __attribute__((ext_vector_type(8)));

static constexpr int B_TOK  = 4096;
static constexpr int E_DIM  = 1024;
static constexpr int N_EXPC = 8;
static constexpr int HID    = 4096;
static constexpr int IMGSZ  = 4096;
static constexpr int NSLOT  = 2 * B_TOK;
static constexpr int NTIL   = 71;          // max 128-row tiles: 64 + 7 remainder tiles

#define DEVI __device__ __forceinline__

DEVI int imin(int a, int b) { return a < b ? a : b; }

DEVI uint16_t f2bf(float f) {
  union { float f; uint32_t u; } v; v.f = f;
  uint32_t u = v.u;
  return (uint16_t)((u + 0x7FFFu + ((u >> 16) & 1u)) >> 16);
}

DEVI float bf2f(uint16_t u) {
  union { uint32_t i; float f; } v; v.i = (uint32_t)u << 16; return v.f;
}

DEVI void gload_lds16(const void* g, void* l) {
  __builtin_amdgcn_global_load_lds((const __attribute__((address_space(1))) void*)g,
                                   (__attribute__((address_space(3))) void*)l, 16, 0, 0);
}

template<int N> DEVI void waitv() {
  if constexpr (N == 0)       asm volatile("s_waitcnt vmcnt(0)" ::: "memory");
  else if constexpr (N == 4)  asm volatile("s_waitcnt vmcnt(4)" ::: "memory");
  else if constexpr (N == 8)  asm volatile("s_waitcnt vmcnt(8)" ::: "memory");
  else if constexpr (N == 10) asm volatile("s_waitcnt vmcnt(10)" ::: "memory");
}

#define BAR() do { __builtin_amdgcn_sched_barrier(0); __builtin_amdgcn_s_barrier(); \
                   __builtin_amdgcn_sched_barrier(0); } while (0)

#define MFMA16(a, b, c) __builtin_amdgcn_mfma_f32_16x16x32_bf16((a), (b), (c), 0, 0, 0)

// ---------------- device helpers reused across merged kernels ----------------
DEVI void transW_body(int bid, const float* W1, const float* W2,
                      const float* We, const float* Wi,
                      uint16_t* W1T, uint16_t* W2T, uint16_t* WeT, uint16_t* WiT,
                      float (*tile)[65])
{
  const float* in; uint16_t* out; int R, C, c0, r0;
  if (bid < 8192) {                       // W1: 8 x [1024][4096]
    int e = bid >> 10, rem = bid & 1023;
    R = 1024; C = 4096;
    c0 = (rem & 63) * 64; r0 = (rem >> 6) * 64;
    in = W1 + (size_t)e * R * C; out = W1T + (size_t)e * R * C;
  } else if (bid < 16384) {               // W2: 8 x [4096][1024]
    int i = bid - 8192; int e = i >> 10, rem = i & 1023;
    R = 4096; C = 1024;
    c0 = (rem & 15) * 64; r0 = (rem >> 4) * 64;
    in = W2 + (size_t)e * R * C; out = W2T + (size_t)e * R * C;
  } else if (bid < 16640) {               // W_enc: [4096][256]
    int i = bid - 16384;
    R = 4096; C = 256;
    c0 = (i & 3) * 64; r0 = (i >> 2) * 64;
    in = We; out = WeT;
  } else {                                // W_img: [1024][256]
    int i = bid - 16640;
    R = 1024; C = 256;
    c0 = (i & 3) * 64; r0 = (i >> 2) * 64;
    in = Wi; out = WiT;
  }
  int t = threadIdx.x;
  #pragma unroll
  for (int i = 0; i < 4; ++i) {
    int rr = i * 16 + (t >> 4), c4 = (t & 15) * 4;
    f32x4 v = *(const f32x4*)&in[(size_t)(r0 + rr) * C + c0 + c4];
    tile[rr][c4 + 0] = v[0]; tile[rr][c4 + 1] = v[1];
    tile[rr][c4 + 2] = v[2]; tile[rr][c4 + 3] = v[3];
  }
  __syncthreads();
  #pragma unroll
  for (int i = 0; i < 2; ++i) {
    int c = i * 32 + (t >> 3), j = t & 7;
    u16x8 o;
    #pragma unroll
    for (int k = 0; k < 8; ++k) o[k] = f2bf(tile[j * 8 + k][c]);
    *(u16x8*)&out[(size_t)(c0 + c) * R + r0 + j * 8] = o;
  }
}

// out[k][e] = sum_m W[k][m] * G[m][e]   (wave per k-row; 4 rows/block)
DEVI void matf_body(int kblk, const float* W, const float* G, float* out)
{
  int k = kblk * 4 + (threadIdx.x >> 6);
  int lane = threadIdx.x & 63;
  float a0 = 0.f, a1 = 0.f, a2 = 0.f, a3 = 0.f, a4 = 0.f, a5 = 0.f, a6 = 0.f, a7 = 0.f;
  for (int m = lane; m < E_DIM; m += 64) {
    float w = W[(size_t)k * E_DIM + m];
    const float* gm = &G[m * 8];
    a0 = __builtin_fmaf(w, gm[0], a0); a1 = __builtin_fmaf(w, gm[1], a1);
    a2 = __builtin_fmaf(w, gm[2], a2); a3 = __builtin_fmaf(w, gm[3], a3);
    a4 = __builtin_fmaf(w, gm[4], a4); a5 = __builtin_fmaf(w, gm[5], a5);
    a6 = __builtin_fmaf(w, gm[6], a6); a7 = __builtin_fmaf(w, gm[7], a7);
  }
  #pragma unroll
  for (int off = 32; off; off >>= 1) {
    a0 += __shfl_xor(a0, off); a1 += __shfl_xor(a1, off);
    a2 += __shfl_xor(a2, off); a3 += __shfl_xor(a3, off);
    a4 += __shfl_xor(a4, off); a5 += __shfl_xor(a5, off);
    a6 += __shfl_xor(a6, off); a7 += __shfl_xor(a7, off);
  }
  if (lane == 0) {
    float* o = &out[k * 8];
    o[0] = a0; o[1] = a1; o[2] = a2; o[3] = a3;
    o[4] = a4; o[5] = a5; o[6] = a6; o[7] = a7;
  }
}

// ---------------- D1: transW || matf1(Wo@Wg) || bvwo || zero ----------------
__global__ __launch_bounds__(256)
void prep1_k(const float* __restrict__ W1, const float* __restrict__ W2,
             const float* __restrict__ We, const float* __restrict__ Wi,
             uint16_t* __restrict__ W1T, uint16_t* __restrict__ W2T,
             uint16_t* __restrict__ WeT, uint16_t* __restrict__ WiT,
             const float* __restrict__ Wo, const float* __restrict__ Wg,
             float* __restrict__ g1c,
             const float* __restrict__ bv, float* __restrict__ part,
             int* __restrict__ counts)
{
  __shared__ float tile[64][65];
  int bid = blockIdx.x;
  if (bid < 16704) {
    transW_body(bid, W1, W2, We, Wi, W1T, W2T, WeT, WiT, tile);
  } else if (bid < 16960) {
    matf_body(bid - 16704, Wo, Wg, g1c);
  } else if (bid < 16968) {
    int b = bid - 16960, t = threadIdx.x;
    f32x4 acc = {0.f, 0.f, 0.f, 0.f};
    for (int k = b * 128; k < b * 128 + 128; ++k) {
      float s = bv[k];
      f32x4 w = *(const f32x4*)&Wo[(size_t)k * E_DIM + t * 4];
      acc[0] = __builtin_fmaf(s, w[0], acc[0]);
      acc[1] = __builtin_fmaf(s, w[1], acc[1]);
      acc[2] = __builtin_fmaf(s, w[2], acc[2]);
      acc[3] = __builtin_fmaf(s, w[3], acc[3]);
    }
    *(f32x4*)&part[(size_t)b * E_DIM + t * 4] = acc;
  } else {
    if (threadIdx.x < 8) counts[threadIdx.x] = 0;
  }
}

// ---------------- D2: matf2(Wv@g1) || fused t1+gbias ----------------
__global__ __launch_bounds__(256)
void prep2_k(const float* __restrict__ Wv, const float* __restrict__ g1c,
             float* __restrict__ G3,
             const float* __restrict__ part, const float* __restrict__ bo,
             const float* __restrict__ Wg, const float* __restrict__ bg,
             float* __restrict__ gb)
{
  int bid = blockIdx.x;
  if (bid < 256) {
    matf_body(bid, Wv, g1c, G3);
  } else {
    __shared__ float t1s[E_DIM];
    int t = threadIdx.x;
    for (int j = t; j < E_DIM; j += 256) {
      float s = bo[j];
      #pragma unroll
      for (int b = 0; b < 8; ++b) s += part[(size_t)b * E_DIM + j];
      t1s[j] = s;
    }
    __syncthreads();
    int wave = t >> 6, lane = t & 63;
    #pragma unroll
    for (int ei = 0; ei < 2; ++ei) {
      int e = wave * 2 + ei;
      float s = 0.f;
      for (int m = lane; m < E_DIM; m += 64) s = __builtin_fmaf(t1s[m], Wg[m * 8 + e], s);
      #pragma unroll
      for (int off = 32; off; off >>= 1) s += __shfl_xor(s, off);
      if (lane == 0) gb[e] = s + bg[e];
    }
  }
}

// ================= D3 merged: enc/img GEMM (896 blocks) || gate (4096 blocks) =================
// bid<896: encR z=bid>>7, y=(bid>>6)&1, x=bid&63.
//   z<6: enc branch (br=z/2, kc=z%2, K=4096, Kc=2048, P=Penc plane z); z==6: img branch.
// bid>=896: gate token b = bid-896 (logits -> softmax -> top2 -> counts).
// LDS unioned: encR 24 KB staging || gate 4.2 KB (sT + lg).
__global__ __launch_bounds__(256, 3)
void encgate_k(const float* __restrict__ F0, const float* __restrict__ F1,
               const float* __restrict__ F2, const float* __restrict__ Fimg,
               const uint16_t* __restrict__ BTe, const uint16_t* __restrict__ BTi,
               float* __restrict__ Penc, float* __restrict__ Pimg,
               const float* __restrict__ text, const float* __restrict__ G3,
               const float* __restrict__ gb, float* __restrict__ gate_out,
               int* __restrict__ topIdx, float* __restrict__ topW,
               int* __restrict__ counts)
{
  __shared__ __align__(16) char shbuf[3 * 8192];
  int bid = blockIdx.x;
  int t = threadIdx.x;

  if (bid >= 896) {                       // ---------------- gate branch ----------------
    int b = bid - 896;
    float* sT = (float*)shbuf;            // E_DIM floats
    float* lg = (float*)(shbuf + E_DIM * 4);
    *(f32x4*)&sT[t * 4] = *(const f32x4*)&text[(size_t)b * E_DIM + t * 4];
    __syncthreads();
    int wave = t >> 6, lane = t & 63;
    #pragma unroll
    for (int ei = 0; ei < 2; ++ei) {
      int e = wave * 2 + ei;
      float s = 0.f;
      for (int k = lane; k < E_DIM; k += 64) s = __builtin_fmaf(sT[k], G3[k * 8 + e], s);
      #pragma unroll
      for (int off = 32; off; off >>= 1) s += __shfl_down(s, off);
      if (lane == 0) lg[e] = s + gb[e];
    }
    __syncthreads();
    if (t == 0) {
      float p[8];
      float mx = lg[0];
      for (int i = 1; i < 8; i++) mx = fmaxf(mx, lg[i]);
      float den = 0.f;
      for (int i = 0; i < 8; i++) { p[i] = __expf(lg[i] - mx); den += p[i]; }
      float inv = 1.f / den;
      for (int i = 0; i < 8; i++) { p[i] *= inv; gate_out[(size_t)b * 8 + i] = p[i]; }
      int i1 = 0;
      for (int i = 1; i < 8; i++) if (p[i] > p[i1]) i1 = i;     // ties -> lower index
      int i2 = (i1 == 0) ? 1 : 0;
      for (int i = 0; i < 8; i++) if (i != i1 && p[i] > p[i2]) i2 = i;
      float ex = __expf(p[i2] - p[i1]);                          // softmax over top-2 probs
      float w1 = 1.f / (1.f + ex), w2 = ex / (1.f + ex);
      topIdx[b * 2] = i1; topIdx[b * 2 + 1] = i2;
      topW[b * 2] = w1;  topW[b * 2 + 1] = w2;
      atomicAdd(&counts[i1], 1);
      atomicAdd(&counts[i2], 1);
    }
    return;
  }

  // ---------------- encR branch ----------------
  int z = bid >> 7, yb = (bid >> 6) & 1, xb = bid & 63;
  const float* Af; const uint16_t* BT; float* P; int K, Kc, k0;
  if (z < 6) {
    int br = z >> 1, kc = z & 1;
    Af = (br == 0) ? F0 : (br == 1) ? F1 : F2;
    BT = BTe; P = Penc + (size_t)z * B_TOK * 256;
    K = IMGSZ; Kc = IMGSZ / 2; k0 = kc * Kc;
  } else {
    Af = Fimg; BT = BTi; P = Pimg;
    K = E_DIM; Kc = E_DIM; k0 = 0;
  }
  int rowBase = xb * 64, nt = yb;

  char* sB = shbuf;
  int wave = t >> 6, lane = t & 63;
  int fr = lane & 15, q4 = lane >> 4;

  const float* gA = Af + (size_t)(rowBase + wave * 16 + fr) * K + k0 + q4 * 8;

  int rloc = t >> 2;
  int ssw = ((t & 3) ^ (rloc & 3)) * 8;
  const uint16_t* gB0 = BT + (size_t)(nt * 128 + rloc) * K + k0 + ssw;
  const uint16_t* gB1 = gB0 + (size_t)64 * K;

  auto STB = [&](int kt, int c) {
    gload_lds16(gB0 + kt * 32, sB + c * 8192 + wave * 1024);
    gload_lds16(gB1 + kt * 32, sB + c * 8192 + 4096 + wave * 1024);
  };

  f32x4 acc[8];
  #pragma unroll
  for (int n = 0; n < 8; ++n) acc[n] = f32x4{0.f, 0.f, 0.f, 0.f};

  int nk = Kc >> 5;
  STB(0, 0); STB(1, 1);
  f32x4 aE0 = *(const f32x4*)(gA),      aE1 = *(const f32x4*)(gA + 4);
  f32x4 aO0 = *(const f32x4*)(gA + 32), aO1 = *(const f32x4*)(gA + 36);
  int c0 = 0, c2 = 2;
  int bRow = (q4 ^ (fr & 3)) * 16;

  auto step = [&](int kt, f32x4& aX0, f32x4& aX1) {
    bool m2 = kt + 2 < nk;
    if (m2) STB(kt + 2, c2);
    bf16x8 a;
    a[0] = (bf16_t)aX0[0]; a[1] = (bf16_t)aX0[1]; a[2] = (bf16_t)aX0[2]; a[3] = (bf16_t)aX0[3];
    a[4] = (bf16_t)aX1[0]; a[5] = (bf16_t)aX1[1]; a[6] = (bf16_t)aX1[2]; a[7] = (bf16_t)aX1[3];
    int kp = m2 ? kt + 2 : kt;
    aX0 = *(const f32x4*)(gA + kp * 32);
    aX1 = *(const f32x4*)(gA + kp * 32 + 4);
    if (m2) waitv<10>(); else waitv<0>();
    BAR();
    const char* bb = sB + c0 * 8192;
    bf16x8 bfr[8];
    #pragma unroll
    for (int n = 0; n < 8; ++n)
      bfr[n] = *(const bf16x8*)(bb + n * 1024 + fr * 64 + bRow);
    #pragma unroll
    for (int n = 0; n < 8; ++n) acc[n] = MFMA16(a, bfr[n], acc[n]);
    BAR();
    c0 = (c0 == 2) ? 0 : c0 + 1;
    c2 = (c2 == 2) ? 0 : c2 + 1;
  };

  for (int kt = 0; kt < nk; kt += 2) {
    step(kt, aE0, aE1);
    step(kt + 1, aO0, aO1);
  }

  #pragma unroll
  for (int n = 0; n < 8; ++n) {
    int col = nt * 128 + n * 16 + fr;
    #pragma unroll
    for (int r = 0; r < 4; ++r) {
      int row = rowBase + wave * 16 + q4 * 4 + r;
      P[(size_t)row * 256 + col] = acc[n][r];
    }
  }
}

// ================= expert GEMM: round-8 proven 128x128, depth-2 counted-vmcnt =================
// EPI: 1=bias+bf16, 3=gelu(exp-form)->bf16 ; supertile raster + XCD swizzle
template<int BN, int EPI, bool GATHER, int NT>
__global__ __launch_bounds__(256, 3)
void gemm_p(const uint16_t* __restrict__ Ab, int lda,
            const uint16_t* __restrict__ BT, void* __restrict__ Cv, int ldc,
            const float* __restrict__ bias, int K,
            const int* __restrict__ meta, const int* __restrict__ perm,
            size_t bStride, int biasStride)
{
  constexpr int HN = BN / 2, FN = BN / 32;
  constexpr int OPS = (BN == 128 ? 4 : 3);
  constexpr int TOTAL = NTIL * NT, Q = TOTAL / 8, FULLB = 64 * NT;
  int bid = blockIdx.x;
  int wg = (bid & 7) * Q + (bid >> 3);            // XCD swizzle
  int mtile, nt;
  if (wg < FULLB) { int rem = wg % (8 * NT); mtile = (wg / (8 * NT)) * 8 + (rem & 7); nt = rem >> 3; }
  else            { int rem = wg - FULLB;    mtile = 64 + rem % 7;                    nt = rem / 7; }
  if (mtile >= meta[0]) return;
  int e = meta[1 + 3 * mtile], rowBase = meta[2 + 3 * mtile], rows = meta[3 + 3 * mtile];
  const uint16_t* Bt = BT + (size_t)e * bStride;
  const float* bi = bias + (size_t)e * (size_t)biasStride;

  constexpr int ABUF = 8192;
  constexpr int BBUF = (BN == 128) ? 8192 : 4096;
  __shared__ __align__(16) char sAraw[3 * ABUF];
  __shared__ __align__(16) char sBraw[3 * BBUF];

  int t = threadIdx.x, wave = t >> 6, lane = t & 63;
  int wr = wave >> 1, wc = wave & 1;

  int rB = t >> 2;
  int slB = ((t & 3) ^ (rB & 3)) * 8;
  const uint16_t* gB0 = Bt + (size_t)(nt * BN + rB) * K + slB;
  const uint16_t* gB1 = Bt + (size_t)(nt * BN + rB + 64) * K + slB;   // BN==128 only

  int r0 = t >> 2, r1 = r0 + 64;
  int sl = ((t & 3) ^ (r0 & 3)) * 8;
  int rr0 = imin(r0, rows - 1), rr1 = imin(r1, rows - 1);
  int car0 = GATHER ? perm[rowBase + rr0] : rowBase + rr0;
  int car1 = GATHER ? perm[rowBase + rr1] : rowBase + rr1;
  const uint16_t* gA0 = Ab + (size_t)car0 * lda + sl;
  const uint16_t* gA1 = Ab + (size_t)car1 * lda + sl;

  char* laW = sAraw + wave * 1024;
  char* lbW = sBraw + wave * 1024;
  auto STAGE = [&](int kt, int c) {
    int ko = kt << 5;
    char* la = laW + c * ABUF;
    char* lb = lbW + c * BBUF;
    gload_lds16(gA0 + ko, la);
    gload_lds16(gA1 + ko, la + 4096);
    gload_lds16(gB0 + ko, lb);
    if constexpr (BN == 128) gload_lds16(gB1 + ko, lb + 4096);
  };

  f32x4 acc[4][FN];
  #pragma unroll
  for (int m = 0; m < 4; m++)
    #pragma unroll
    for (int n = 0; n < FN; n++)
      acc[m][n] = f32x4{0.f, 0.f, 0.f, 0.f};

  STAGE(0, 0);
  STAGE(1, 1);

  int fr = lane & 15;
  int rdoff = ((lane >> 4) ^ (lane & 3)) * 16;
  int c0 = 0, c2 = 2;
  int nk = K >> 5;

  for (int kt = 0; kt < nk; ++kt) {
    if (kt + 2 < nk) { STAGE(kt + 2, c2); waitv<2 * OPS>(); }
    else if (kt + 1 < nk) waitv<OPS>();
    else waitv<0>();
    BAR();

    const char* bA = sAraw + c0 * ABUF;
    const char* bB = sBraw + c0 * BBUF;
    bf16x8 af[4], bfr[FN];
    #pragma unroll
    for (int m = 0; m < 4; m++)
      af[m] = *(const bf16x8*)(bA + (wr * 64 + m * 16 + fr) * 64 + rdoff);
    #pragma unroll
    for (int n = 0; n < FN; n++)
      bfr[n] = *(const bf16x8*)(bB + (wc * HN + n * 16 + fr) * 64 + rdoff);
    #pragma unroll
    for (int m = 0; m < 4; m++)
      #pragma unroll
      for (int n = 0; n < FN; n++)
        acc[m][n] = MFMA16(af[m], bfr[n], acc[m][n]);

    BAR();
    c0 = (c0 == 2) ? 0 : c0 + 1;
    c2 = (c2 == 2) ? 0 : c2 + 1;
  }

  // epilogue: C/D layout col=lane&15, row=(lane>>4)*4+reg (m89-verified)
  #pragma unroll
  for (int m = 0; m < 4; m++) {
    int lrow = wr * 64 + m * 16 + (lane >> 4) * 4;
    #pragma unroll
    for (int n = 0; n < FN; n++) {
      int col = nt * BN + wc * HN + n * 16 + (lane & 15);
      float bval = bi[col];
      #pragma unroll
      for (int r = 0; r < 4; r++) {
        int lr = lrow + r;
        if (lr >= rows) continue;
        float v = acc[m][n][r] + bval;
        size_t cr = (size_t)(rowBase + lr) * ldc + col;
        if (EPI == 3) {   // gelu(tanh) == v * sigmoid(1.5957691*(v + 0.044715 v^3))
          float u = v + 0.044715f * v * v * v;
          v = v / (1.f + __expf(-1.5957691216057308f * u));
          ((uint16_t*)Cv)[cr] = f2bf(v);
        } else {
          ((uint16_t*)Cv)[cr] = f2bf(v);
        }
      }
    }
  }
}

// merged reduce + post: y<3 -> enc reduce (SK=2), y==3 -> img (SK=1, silu),
// y==4 -> post (x==0: imploss, x==1: scanfill)
__global__ __launch_bounds__(256)
void redupost_k(const float* __restrict__ Penc, const float* __restrict__ Pimg,
                const float* __restrict__ bEnc, const float* __restrict__ bImg,
                uint16_t* __restrict__ xb,
                const float* __restrict__ gate_out, float* __restrict__ out_loss,
                const int* __restrict__ counts, const int* __restrict__ topIdx,
                const float* __restrict__ topW,
                int* __restrict__ meta, int* __restrict__ perm,
                int* __restrict__ slotOf)
{
  int y = blockIdx.y, t = threadIdx.x;
  if (y < 4) {
    int row = blockIdx.x * 4 + (t >> 6);
    int c4 = (t & 63) * 4;
    bool img = (y == 3);
    const float* bias = img ? bImg : bEnc;
    f32x4 s = *(const f32x4*)&bias[c4];
    if (img) {
      s += *(const f32x4*)&Pimg[(size_t)row * 256 + c4];
      #pragma unroll
      for (int j = 0; j < 4; ++j) s[j] = s[j] / (1.f + __expf(-s[j]));
    } else {
      const float* p = Penc + (size_t)y * 2 * B_TOK * 256 + (size_t)row * 256 + c4;
      s += *(const f32x4*)p;
      s += *(const f32x4*)(p + (size_t)B_TOK * 256);
    }
    ushort4 o;
    o.x = f2bf(s[0]); o.y = f2bf(s[1]); o.z = f2bf(s[2]); o.w = f2bf(s[3]);
    *(ushort4*)&xb[(size_t)row * E_DIM + y * 256 + c4] = o;
    return;
  }
  if (blockIdx.x == 0) {                       // imploss
    float s[8] = {0.f, 0.f, 0.f, 0.f, 0.f, 0.f, 0.f, 0.f};
    for (int b = t; b < B_TOK; b += 256) {
      const float* g = &gate_out[(size_t)b * 8];
      #pragma unroll
      for (int e = 0; e < 8; ++e) s[e] += g[e];
    }
    __shared__ float red[8][256];
    #pragma unroll
    for (int e = 0; e < 8; ++e) red[e][t] = s[e];
    __syncthreads();
    for (int off = 128; off; off >>= 1) {
      if (t < off)
        #pragma unroll
        for (int e = 0; e < 8; ++e) red[e][t] += red[e][t + off];
      __syncthreads();
    }
    if (t == 0) {
      float m = 0.f;
      for (int e = 0; e < 8; e++) m += red[e][0];
      m *= 0.125f;
      float v = 0.f;
      for (int e = 0; e < 8; e++) { float d = red[e][0] - m; v += d * d; }
      v /= 7.f;                                  // ddof=1
      out_loss[0] = 0.01f * v / (m * m);
    }
  } else if (blockIdx.x == 1) {                // scanfill
    __shared__ int sBases[8];
    __shared__ int sCursor[8];
    if (t == 0) {
      int a = 0, nt = 0;
      for (int e = 0; e < 8; e++) {
        sBases[e] = a; sCursor[e] = 0;
        int c = counts[e];
        for (int j = 0; j < c; j += 128) {
          meta[1 + 3 * nt] = e;
          meta[2 + 3 * nt] = a + j;
          meta[3 + 3 * nt] = (c - j < 128) ? (c - j) : 128;
          nt++;
        }
        a += c;
      }
      meta[0] = nt;
    }
    __syncthreads();
    for (int b = t; b < B_TOK; b += 256) {
      #pragma unroll
      for (int j = 0; j < 2; j++) {
        int e = topIdx[b * 2 + j];
        int pos = atomicAdd(&sCursor[e], 1);
        int slot = sBases[e] + pos;
        perm[slot] = b;
        slotOf[b * 2 + j] = slot;
      }
    }
  }
}

// weighted top-2 mix from bf16 Yg (bias already added inside expert L2 GEMM)
__global__ __launch_bounds__(256)
void combine_k(const uint16_t* __restrict__ Yg, const int* __restrict__ slotOf,
               const float* __restrict__ topW, float* __restrict__ y)
{
  int b = blockIdx.x, t = threadIdx.x;
  int s0 = slotOf[b * 2], s1 = slotOf[b * 2 + 1];
  float w0 = topW[b * 2], w1 = topW[b * 2 + 1];
  ushort4 ua = *(const ushort4*)&Yg[(size_t)s0 * E_DIM + t * 4];
  ushort4 uc = *(const ushort4*)&Yg[(size_t)s1 * E_DIM + t * 4];
  f32x4 r;
  r[0] = bf2f(ua.x) * w0 + bf2f(uc.x) * w1;
  r[1] = bf2f(ua.y) * w0 + bf2f(uc.y) * w1;
  r[2] = bf2f(ua.z) * w0 + bf2f(uc.z) * w1;
  r[3] = bf2f(ua.w) * w0 + bf2f(uc.w) * w1;
  *(f32x4*)&y[(size_t)b * E_DIM + t * 4] = r;
}

// ---------------- host ----------------
extern "C" void kernel_launch(void* const* d_in, const int* in_sizes, int n_in,
                              void* d_out, int out_size, void* d_ws, size_t ws_size,
                              hipStream_t stream)
{
  (void)in_sizes; (void)n_in; (void)out_size;
  const float* src   = (const float*)d_in[0];
  const float* tgt   = (const float*)d_in[1];
  const float* bgr   = (const float*)d_in[2];
  const float* image = (const float*)d_in[3];
  const float* text  = (const float*)d_in[4];
  const float* W_enc = (const float*)d_in[5];
  const float* b_enc = (const float*)d_in[6];
  const float* W_img = (const float*)d_in[7];
  const float* b_img = (const float*)d_in[8];
  // d_in[9..12]: Wq,bq,Wk,bk — dead (softmax over length-1 key axis == 1)
  const float* Wv    = (const float*)d_in[13];
  const float* bv    = (const float*)d_in[14];
  const float* Wo    = (const float*)d_in[15];
  const float* bo    = (const float*)d_in[16];
  const float* Wg    = (const float*)d_in[17];
  const float* bgg   = (const float*)d_in[18];
  const float* W1    = (const float*)d_in[19];
  const float* b1    = (const float*)d_in[20];
  const float* W2    = (const float*)d_in[21];
  const float* b2    = (const float*)d_in[22];

  float* out_y    = (float*)d_out;
  float* out_gate = out_y + (size_t)B_TOK * E_DIM;
  float* out_loss = out_gate + (size_t)B_TOK * N_EXPC;

  char* p = (char*)d_ws;
  auto alloc = [&](size_t bytes) { char* r = p; p += (bytes + 255) & ~(size_t)255; return r; };
  uint16_t* WencT = (uint16_t*)alloc((size_t)256 * IMGSZ * 2);
  uint16_t* WimgT = (uint16_t*)alloc((size_t)256 * E_DIM * 2);
  uint16_t* W1T   = (uint16_t*)alloc((size_t)N_EXPC * HID * E_DIM * 2);
  uint16_t* W2T   = (uint16_t*)alloc((size_t)N_EXPC * E_DIM * HID * 2);
  float* part  = (float*)alloc((size_t)8 * E_DIM * 4);
  float* g1c   = (float*)alloc((size_t)E_DIM * 8 * 4);
  float* G3    = (float*)alloc((size_t)E_DIM * 8 * 4);
  float* gbv   = (float*)alloc(64 * 4);
  int*   topIdx = (int*)alloc(B_TOK * 2 * 4);
  float* topW   = (float*)alloc(B_TOK * 2 * 4);
  int*   slotOf = (int*)alloc(B_TOK * 2 * 4);
  int*   counts = (int*)alloc(64 * 4);
  int*   meta   = (int*)alloc((1 + 3 * (NTIL + 1)) * 4 + 64);
  int*   perm   = (int*)alloc(NSLOT * 4);
  uint16_t* xbf  = (uint16_t*)alloc((size_t)B_TOK * E_DIM * 2);
  uint16_t* Hbuf = (uint16_t*)alloc((size_t)NSLOT * HID * 2);
  // union region: enc partials (7 planes, 28 MB) then expert output Yg bf16 (16 MB)
  char* uni = alloc((size_t)7 * B_TOK * 256 * 4);
  float* Penc = (float*)uni;                               // 6 planes * 4 MB
  float* Pimg = Penc + (size_t)6 * B_TOK * 256;            // 1 plane
  uint16_t* Yg = (uint16_t*)uni;                           // reused after redupost
  if ((size_t)(p - (char*)d_ws) > ws_size) return;   // ws too small: fail visibly

  // D1: transW || matf1 || bvwo || zero-counts
  prep1_k<<<dim3(16969), 256, 0, stream>>>(W1, W2, W_enc, W_img, W1T, W2T, WencT, WimgT,
                                           Wo, Wg, g1c, bv, part, counts);
  // D2: matf2 || fused t1+gbias
  prep2_k<<<dim3(257), 256, 0, stream>>>(Wv, g1c, G3, part, bo, Wg, bgg, gbv);
  // D3: enc+img GEMMs (896 blocks) || gate (4096 blocks) — mutually independent
  encgate_k<<<dim3(896 + B_TOK), 256, 0, stream>>>(
      src, tgt, bgr, image, WencT, WimgT, Penc, Pimg,
      text, G3, gbv, out_gate, topIdx, topW, counts);
  // D4: merged reduce + post (imploss, scanfill)
  redupost_k<<<dim3(B_TOK / 4, 5), 256, 0, stream>>>(
      Penc, Pimg, b_enc, b_img, xbf,
      out_gate, out_loss, counts, topIdx, topW, meta, perm, slotOf);

  // D5/D6: sparse top-2 expert MLPs (round-8 proven kernels); L2 emits bf16
  gemm_p<128, 3, true, HID / 128><<<dim3(NTIL * (HID / 128)), 256, 0, stream>>>(
      xbf, E_DIM, W1T, Hbuf, HID, b1, E_DIM, meta, perm, (size_t)HID * E_DIM, HID);
  gemm_p<128, 1, false, E_DIM / 128><<<dim3(NTIL * (E_DIM / 128)), 256, 0, stream>>>(
      Hbuf, HID, W2T, Yg, E_DIM, b2, HID, meta, perm, (size_t)E_DIM * HID, E_DIM);

  // D7: combine
  combine_k<<<B_TOK, 256, 0, stream>>>(Yg, slotOf, topW, out_y);
}

// Round 20
// 571.912 us; speedup vs baseline: 1.2592x; 1.0196x over previous
//
#include <hip/hip_runtime.h>
#include <hip/hip_bf16.h>
#include <stdint.h>

typedef __bf16 bf16_t;
typedef bf16_t bf16x8 __attribute__((ext_vector_type(8)));
typedef float f32x4 __attribute__((ext_vector_type(4)));
typedef uint16_t u16x8 __attribute__((ext_vector_type(8)));

static constexpr int B_TOK  = 4096;
static constexpr int E_DIM  = 1024;
static constexpr int N_EXPC = 8;
static constexpr int HID    = 4096;
static constexpr int IMGSZ  = 4096;
static constexpr int NSLOT  = 2 * B_TOK;
static constexpr int NTIL   = 71;          // max 128-row tiles: 64 + 7 remainder tiles

#define DEVI __device__ __forceinline__

DEVI int imin(int a, int b) { return a < b ? a : b; }

DEVI uint16_t f2bf(float f) {
  union { float f; uint32_t u; } v; v.f = f;
  uint32_t u = v.u;
  return (uint16_t)((u + 0x7FFFu + ((u >> 16) & 1u)) >> 16);
}

DEVI float bf2f(uint16_t u) {
  union { uint32_t i; float f; } v; v.i = (uint32_t)u << 16; return v.f;
}

DEVI void gload_lds16(const void* g, void* l) {
  __builtin_amdgcn_global_load_lds((const __attribute__((address_space(1))) void*)g,
                                   (__attribute__((address_space(3))) void*)l, 16, 0, 0);
}

template<int N> DEVI void waitv() {
  if constexpr (N == 0)       asm volatile("s_waitcnt vmcnt(0)" ::: "memory");
  else if constexpr (N == 4)  asm volatile("s_waitcnt vmcnt(4)" ::: "memory");
  else if constexpr (N == 8)  asm volatile("s_waitcnt vmcnt(8)" ::: "memory");
  else if constexpr (N == 10) asm volatile("s_waitcnt vmcnt(10)" ::: "memory");
}

#define BAR() do { __builtin_amdgcn_sched_barrier(0); __builtin_amdgcn_s_barrier(); \
                   __builtin_amdgcn_sched_barrier(0); } while (0)

#define MFMA16(a, b, c) __builtin_amdgcn_mfma_f32_16x16x32_bf16((a), (b), (c), 0, 0, 0)

// ---------------- device helpers reused across merged kernels ----------------
DEVI void transW_body(int bid, const float* W1, const float* W2,
                      const float* We, const float* Wi,
                      uint16_t* W1T, uint16_t* W2T, uint16_t* WeT, uint16_t* WiT,
                      float (*tile)[65])
{
  const float* in; uint16_t* out; int R, C, c0, r0;
  if (bid < 8192) {                       // W1: 8 x [1024][4096]
    int e = bid >> 10, rem = bid & 1023;
    R = 1024; C = 4096;
    c0 = (rem & 63) * 64; r0 = (rem >> 6) * 64;
    in = W1 + (size_t)e * R * C; out = W1T + (size_t)e * R * C;
  } else if (bid < 16384) {               // W2: 8 x [4096][1024]
    int i = bid - 8192; int e = i >> 10, rem = i & 1023;
    R = 4096; C = 1024;
    c0 = (rem & 15) * 64; r0 = (rem >> 4) * 64;
    in = W2 + (size_t)e * R * C; out = W2T + (size_t)e * R * C;
  } else if (bid < 16640) {               // W_enc: [4096][256]
    int i = bid - 16384;
    R = 4096; C = 256;
    c0 = (i & 3) * 64; r0 = (i >> 2) * 64;
    in = We; out = WeT;
  } else {                                // W_img: [1024][256]
    int i = bid - 16640;
    R = 1024; C = 256;
    c0 = (i & 3) * 64; r0 = (i >> 2) * 64;
    in = Wi; out = WiT;
  }
  int t = threadIdx.x;
  #pragma unroll
  for (int i = 0; i < 4; ++i) {
    int rr = i * 16 + (t >> 4), c4 = (t & 15) * 4;
    f32x4 v = *(const f32x4*)&in[(size_t)(r0 + rr) * C + c0 + c4];
    tile[rr][c4 + 0] = v[0]; tile[rr][c4 + 1] = v[1];
    tile[rr][c4 + 2] = v[2]; tile[rr][c4 + 3] = v[3];
  }
  __syncthreads();
  #pragma unroll
  for (int i = 0; i < 2; ++i) {
    int c = i * 32 + (t >> 3), j = t & 7;
    u16x8 o;
    #pragma unroll
    for (int k = 0; k < 8; ++k) o[k] = f2bf(tile[j * 8 + k][c]);
    *(u16x8*)&out[(size_t)(c0 + c) * R + r0 + j * 8] = o;
  }
}

// out[k][e] = sum_m W[k][m] * G[m][e]   (wave per k-row; 4 rows/block)
DEVI void matf_body(int kblk, const float* W, const float* G, float* out)
{
  int k = kblk * 4 + (threadIdx.x >> 6);
  int lane = threadIdx.x & 63;
  float a0 = 0.f, a1 = 0.f, a2 = 0.f, a3 = 0.f, a4 = 0.f, a5 = 0.f, a6 = 0.f, a7 = 0.f;
  for (int m = lane; m < E_DIM; m += 64) {
    float w = W[(size_t)k * E_DIM + m];
    const float* gm = &G[m * 8];
    a0 = __builtin_fmaf(w, gm[0], a0); a1 = __builtin_fmaf(w, gm[1], a1);
    a2 = __builtin_fmaf(w, gm[2], a2); a3 = __builtin_fmaf(w, gm[3], a3);
    a4 = __builtin_fmaf(w, gm[4], a4); a5 = __builtin_fmaf(w, gm[5], a5);
    a6 = __builtin_fmaf(w, gm[6], a6); a7 = __builtin_fmaf(w, gm[7], a7);
  }
  #pragma unroll
  for (int off = 32; off; off >>= 1) {
    a0 += __shfl_xor(a0, off); a1 += __shfl_xor(a1, off);
    a2 += __shfl_xor(a2, off); a3 += __shfl_xor(a3, off);
    a4 += __shfl_xor(a4, off); a5 += __shfl_xor(a5, off);
    a6 += __shfl_xor(a6, off); a7 += __shfl_xor(a7, off);
  }
  if (lane == 0) {
    float* o = &out[k * 8];
    o[0] = a0; o[1] = a1; o[2] = a2; o[3] = a3;
    o[4] = a4; o[5] = a5; o[6] = a6; o[7] = a7;
  }
}

// ---------------- D1: transW || matf1(Wo@Wg) || bvwo || zero ----------------
__global__ __launch_bounds__(256)
void prep1_k(const float* __restrict__ W1, const float* __restrict__ W2,
             const float* __restrict__ We, const float* __restrict__ Wi,
             uint16_t* __restrict__ W1T, uint16_t* __restrict__ W2T,
             uint16_t* __restrict__ WeT, uint16_t* __restrict__ WiT,
             const float* __restrict__ Wo, const float* __restrict__ Wg,
             float* __restrict__ g1c,
             const float* __restrict__ bv, float* __restrict__ part,
             int* __restrict__ counts)
{
  __shared__ float tile[64][65];
  int bid = blockIdx.x;
  if (bid < 16704) {
    transW_body(bid, W1, W2, We, Wi, W1T, W2T, WeT, WiT, tile);
  } else if (bid < 16960) {
    matf_body(bid - 16704, Wo, Wg, g1c);
  } else if (bid < 16968) {
    int b = bid - 16960, t = threadIdx.x;
    f32x4 acc = {0.f, 0.f, 0.f, 0.f};
    for (int k = b * 128; k < b * 128 + 128; ++k) {
      float s = bv[k];
      f32x4 w = *(const f32x4*)&Wo[(size_t)k * E_DIM + t * 4];
      acc[0] = __builtin_fmaf(s, w[0], acc[0]);
      acc[1] = __builtin_fmaf(s, w[1], acc[1]);
      acc[2] = __builtin_fmaf(s, w[2], acc[2]);
      acc[3] = __builtin_fmaf(s, w[3], acc[3]);
    }
    *(f32x4*)&part[(size_t)b * E_DIM + t * 4] = acc;
  } else {
    if (threadIdx.x < 8) counts[threadIdx.x] = 0;
  }
}

// ---------------- D2: matf2(Wv@g1) || fused t1+gbias ----------------
__global__ __launch_bounds__(256)
void prep2_k(const float* __restrict__ Wv, const float* __restrict__ g1c,
             float* __restrict__ G3,
             const float* __restrict__ part, const float* __restrict__ bo,
             const float* __restrict__ Wg, const float* __restrict__ bg,
             float* __restrict__ gb)
{
  int bid = blockIdx.x;
  if (bid < 256) {
    matf_body(bid, Wv, g1c, G3);
  } else {
    __shared__ float t1s[E_DIM];
    int t = threadIdx.x;
    for (int j = t; j < E_DIM; j += 256) {
      float s = bo[j];
      #pragma unroll
      for (int b = 0; b < 8; ++b) s += part[(size_t)b * E_DIM + j];
      t1s[j] = s;
    }
    __syncthreads();
    int wave = t >> 6, lane = t & 63;
    #pragma unroll
    for (int ei = 0; ei < 2; ++ei) {
      int e = wave * 2 + ei;
      float s = 0.f;
      for (int m = lane; m < E_DIM; m += 64) s = __builtin_fmaf(t1s[m], Wg[m * 8 + e], s);
      #pragma unroll
      for (int off = 32; off; off >>= 1) s += __shfl_xor(s, off);
      if (lane == 0) gb[e] = s + bg[e];
    }
  }
}

// ================= D3 merged: enc/img GEMM (896 blocks, BK=64) || gate (4096 blocks) ==========
// bid<896: encR z=bid>>7, y=(bid>>6)&1, x=bid&63.
//   z<6: enc branch (br=z/2, kc=z%2, K=4096, Kc=2048); z==6: img branch (K=Kc=1024).
//   BK=64: halved barrier density vs BK=32 (16 MFMA between barrier pairs). B staged in
//   2x16KB LDS buffers (occupancy preserved); A register-streamed (even/odd sets).
//   Ledger: 4 B-gloads + 4 A-loads per step; waitv<8> retires exactly the prior step's 8.
//   8-slice XOR swizzle: pre-swizzled global source + linear LDS + matching read XOR.
// bid>=896: gate token b = bid-896 (logits -> softmax -> top2 -> counts).
__global__ __launch_bounds__(256, 3)
void encgate_k(const float* __restrict__ F0, const float* __restrict__ F1,
               const float* __restrict__ F2, const float* __restrict__ Fimg,
               const uint16_t* __restrict__ BTe, const uint16_t* __restrict__ BTi,
               float* __restrict__ Penc, float* __restrict__ Pimg,
               const float* __restrict__ text, const float* __restrict__ G3,
               const float* __restrict__ gb, float* __restrict__ gate_out,
               int* __restrict__ topIdx, float* __restrict__ topW,
               int* __restrict__ counts)
{
  __shared__ __align__(16) char shbuf[2 * 16384];
  int bid = blockIdx.x;
  int t = threadIdx.x;

  if (bid >= 896) {                       // ---------------- gate branch ----------------
    int b = bid - 896;
    float* sT = (float*)shbuf;            // E_DIM floats
    float* lg = (float*)(shbuf + E_DIM * 4);
    *(f32x4*)&sT[t * 4] = *(const f32x4*)&text[(size_t)b * E_DIM + t * 4];
    __syncthreads();
    int wave = t >> 6, lane = t & 63;
    #pragma unroll
    for (int ei = 0; ei < 2; ++ei) {
      int e = wave * 2 + ei;
      float s = 0.f;
      for (int k = lane; k < E_DIM; k += 64) s = __builtin_fmaf(sT[k], G3[k * 8 + e], s);
      #pragma unroll
      for (int off = 32; off; off >>= 1) s += __shfl_down(s, off);
      if (lane == 0) lg[e] = s + gb[e];
    }
    __syncthreads();
    if (t == 0) {
      float p[8];
      float mx = lg[0];
      for (int i = 1; i < 8; i++) mx = fmaxf(mx, lg[i]);
      float den = 0.f;
      for (int i = 0; i < 8; i++) { p[i] = __expf(lg[i] - mx); den += p[i]; }
      float inv = 1.f / den;
      for (int i = 0; i < 8; i++) { p[i] *= inv; gate_out[(size_t)b * 8 + i] = p[i]; }
      int i1 = 0;
      for (int i = 1; i < 8; i++) if (p[i] > p[i1]) i1 = i;     // ties -> lower index
      int i2 = (i1 == 0) ? 1 : 0;
      for (int i = 0; i < 8; i++) if (i != i1 && p[i] > p[i2]) i2 = i;
      float ex = __expf(p[i2] - p[i1]);                          // softmax over top-2 probs
      float w1 = 1.f / (1.f + ex), w2 = ex / (1.f + ex);
      topIdx[b * 2] = i1; topIdx[b * 2 + 1] = i2;
      topW[b * 2] = w1;  topW[b * 2 + 1] = w2;
      atomicAdd(&counts[i1], 1);
      atomicAdd(&counts[i2], 1);
    }
    return;
  }

  // ---------------- encR branch: BK=64, 2-buffer, even/odd A register sets ----------------
  int z = bid >> 7, yb = (bid >> 6) & 1, xb = bid & 63;
  const float* Af; const uint16_t* BT; float* P; int K, Kc, k0;
  if (z < 6) {
    int br = z >> 1, kc = z & 1;
    Af = (br == 0) ? F0 : (br == 1) ? F1 : F2;
    BT = BTe; P = Penc + (size_t)z * B_TOK * 256;
    K = IMGSZ; Kc = IMGSZ / 2; k0 = kc * Kc;
  } else {
    Af = Fimg; BT = BTi; P = Pimg;
    K = E_DIM; Kc = E_DIM; k0 = 0;
  }
  int rowBase = xb * 64, nt = yb;

  char* sB = shbuf;
  int wave = t >> 6, lane = t & 63;
  int fr = lane & 15, q4 = lane >> 4;

  const float* gA = Af + (size_t)(rowBase + wave * 16 + fr) * K + k0;

  // B staging: 4 gloads cover [128 rows][64 elems]; gload j -> rows j*32 + (t>>3),
  // LDS linear (byte = row*128 + (t&7)*16), global slice pre-swizzled by (row&7).
  int r8 = t >> 3;
  int sg = ((t & 7) ^ (r8 & 7)) * 8;
  const uint16_t* gBp0 = BT + (size_t)(nt * 128 +  0 + r8) * K + k0 + sg;
  const uint16_t* gBp1 = BT + (size_t)(nt * 128 + 32 + r8) * K + k0 + sg;
  const uint16_t* gBp2 = BT + (size_t)(nt * 128 + 64 + r8) * K + k0 + sg;
  const uint16_t* gBp3 = BT + (size_t)(nt * 128 + 96 + r8) * K + k0 + sg;

  auto STAGE = [&](int kt, int c) {
    char* base = sB + c * 16384 + wave * 1024;
    gload_lds16(gBp0 + kt * 64, base);
    gload_lds16(gBp1 + kt * 64, base + 4096);
    gload_lds16(gBp2 + kt * 64, base + 8192);
    gload_lds16(gBp3 + kt * 64, base + 12288);
  };

  f32x4 acc[8];
  #pragma unroll
  for (int n = 0; n < 8; ++n) acc[n] = f32x4{0.f, 0.f, 0.f, 0.f};

  int nk = Kc >> 6;                        // enc: 32, img: 16 (both even)

  f32x4 paE[4], paO[4];
  auto LA = [&](f32x4* pa, int kt) {
    int ko = (kt << 6) + q4 * 8;
    pa[0] = *(const f32x4*)(gA + ko);
    pa[1] = *(const f32x4*)(gA + ko + 4);
    pa[2] = *(const f32x4*)(gA + ko + 32);
    pa[3] = *(const f32x4*)(gA + ko + 36);
  };
  auto COMP = [&](const f32x4* pa, int c) {
    const char* bb = sB + c * 16384;
    #pragma unroll
    for (int ks = 0; ks < 2; ++ks) {
      bf16x8 a;
      a[0] = (bf16_t)pa[ks * 2][0]; a[1] = (bf16_t)pa[ks * 2][1];
      a[2] = (bf16_t)pa[ks * 2][2]; a[3] = (bf16_t)pa[ks * 2][3];
      a[4] = (bf16_t)pa[ks * 2 + 1][0]; a[5] = (bf16_t)pa[ks * 2 + 1][1];
      a[6] = (bf16_t)pa[ks * 2 + 1][2]; a[7] = (bf16_t)pa[ks * 2 + 1][3];
      int sidx = (ks * 4 + q4) ^ (fr & 7);
      #pragma unroll
      for (int n = 0; n < 8; ++n) {
        bf16x8 b = *(const bf16x8*)(bb + (n * 16 + fr) * 128 + sidx * 16);
        acc[n] = MFMA16(a, b, acc[n]);
      }
    }
  };

  STAGE(0, 0);
  LA(paE, 0);
  for (int kt = 0; kt < nk; kt += 2) {
    STAGE(kt + 1, 1); LA(paO, kt + 1);
    waitv<8>();                            // retires B(kt)+A(even) -> buf0 + paE ready
    BAR();
    COMP(paE, 0);
    BAR();                                 // buf0 readers done before next overwrite
    bool m2 = kt + 2 < nk;
    if (m2) { STAGE(kt + 2, 0); LA(paE, kt + 2); waitv<8>(); }
    else waitv<0>();
    BAR();
    COMP(paO, 1);
    BAR();
  }

  #pragma unroll
  for (int n = 0; n < 8; ++n) {
    int col = nt * 128 + n * 16 + fr;
    #pragma unroll
    for (int r = 0; r < 4; ++r) {
      int row = rowBase + wave * 16 + q4 * 4 + r;
      P[(size_t)row * 256 + col] = acc[n][r];
    }
  }
}

// ================= expert GEMM: round-8 proven 128x128, depth-2 counted-vmcnt =================
// EPI: 1=bias+bf16, 3=gelu(exp-form)->bf16 ; supertile raster + XCD swizzle
template<int BN, int EPI, bool GATHER, int NT>
__global__ __launch_bounds__(256, 3)
void gemm_p(const uint16_t* __restrict__ Ab, int lda,
            const uint16_t* __restrict__ BT, void* __restrict__ Cv, int ldc,
            const float* __restrict__ bias, int K,
            const int* __restrict__ meta, const int* __restrict__ perm,
            size_t bStride, int biasStride)
{
  constexpr int HN = BN / 2, FN = BN / 32;
  constexpr int OPS = (BN == 128 ? 4 : 3);
  constexpr int TOTAL = NTIL * NT, Q = TOTAL / 8, FULLB = 64 * NT;
  int bid = blockIdx.x;
  int wg = (bid & 7) * Q + (bid >> 3);            // XCD swizzle
  int mtile, nt;
  if (wg < FULLB) { int rem = wg % (8 * NT); mtile = (wg / (8 * NT)) * 8 + (rem & 7); nt = rem >> 3; }
  else            { int rem = wg - FULLB;    mtile = 64 + rem % 7;                    nt = rem / 7; }
  if (mtile >= meta[0]) return;
  int e = meta[1 + 3 * mtile], rowBase = meta[2 + 3 * mtile], rows = meta[3 + 3 * mtile];
  const uint16_t* Bt = BT + (size_t)e * bStride;
  const float* bi = bias + (size_t)e * (size_t)biasStride;

  constexpr int ABUF = 8192;
  constexpr int BBUF = (BN == 128) ? 8192 : 4096;
  __shared__ __align__(16) char sAraw[3 * ABUF];
  __shared__ __align__(16) char sBraw[3 * BBUF];

  int t = threadIdx.x, wave = t >> 6, lane = t & 63;
  int wr = wave >> 1, wc = wave & 1;

  int rB = t >> 2;
  int slB = ((t & 3) ^ (rB & 3)) * 8;
  const uint16_t* gB0 = Bt + (size_t)(nt * BN + rB) * K + slB;
  const uint16_t* gB1 = Bt + (size_t)(nt * BN + rB + 64) * K + slB;   // BN==128 only

  int r0 = t >> 2, r1 = r0 + 64;
  int sl = ((t & 3) ^ (r0 & 3)) * 8;
  int rr0 = imin(r0, rows - 1), rr1 = imin(r1, rows - 1);
  int car0 = GATHER ? perm[rowBase + rr0] : rowBase + rr0;
  int car1 = GATHER ? perm[rowBase + rr1] : rowBase + rr1;
  const uint16_t* gA0 = Ab + (size_t)car0 * lda + sl;
  const uint16_t* gA1 = Ab + (size_t)car1 * lda + sl;

  char* laW = sAraw + wave * 1024;
  char* lbW = sBraw + wave * 1024;
  auto STAGE = [&](int kt, int c) {
    int ko = kt << 5;
    char* la = laW + c * ABUF;
    char* lb = lbW + c * BBUF;
    gload_lds16(gA0 + ko, la);
    gload_lds16(gA1 + ko, la + 4096);
    gload_lds16(gB0 + ko, lb);
    if constexpr (BN == 128) gload_lds16(gB1 + ko, lb + 4096);
  };

  f32x4 acc[4][FN];
  #pragma unroll
  for (int m = 0; m < 4; m++)
    #pragma unroll
    for (int n = 0; n < FN; n++)
      acc[m][n] = f32x4{0.f, 0.f, 0.f, 0.f};

  STAGE(0, 0);
  STAGE(1, 1);

  int fr = lane & 15;
  int rdoff = ((lane >> 4) ^ (lane & 3)) * 16;
  int c0 = 0, c2 = 2;
  int nk = K >> 5;

  for (int kt = 0; kt < nk; ++kt) {
    if (kt + 2 < nk) { STAGE(kt + 2, c2); waitv<2 * OPS>(); }
    else if (kt + 1 < nk) waitv<OPS>();
    else waitv<0>();
    BAR();

    const char* bA = sAraw + c0 * ABUF;
    const char* bB = sBraw + c0 * BBUF;
    bf16x8 af[4], bfr[FN];
    #pragma unroll
    for (int m = 0; m < 4; m++)
      af[m] = *(const bf16x8*)(bA + (wr * 64 + m * 16 + fr) * 64 + rdoff);
    #pragma unroll
    for (int n = 0; n < FN; n++)
      bfr[n] = *(const bf16x8*)(bB + (wc * HN + n * 16 + fr) * 64 + rdoff);
    #pragma unroll
    for (int m = 0; m < 4; m++)
      #pragma unroll
      for (int n = 0; n < FN; n++)
        acc[m][n] = MFMA16(af[m], bfr[n], acc[m][n]);

    BAR();
    c0 = (c0 == 2) ? 0 : c0 + 1;
    c2 = (c2 == 2) ? 0 : c2 + 1;
  }

  // epilogue: C/D layout col=lane&15, row=(lane>>4)*4+reg (m89-verified)
  #pragma unroll
  for (int m = 0; m < 4; m++) {
    int lrow = wr * 64 + m * 16 + (lane >> 4) * 4;
    #pragma unroll
    for (int n = 0; n < FN; n++) {
      int col = nt * BN + wc * HN + n * 16 + (lane & 15);
      float bval = bi[col];
      #pragma unroll
      for (int r = 0; r < 4; r++) {
        int lr = lrow + r;
        if (lr >= rows) continue;
        float v = acc[m][n][r] + bval;
        size_t cr = (size_t)(rowBase + lr) * ldc + col;
        if (EPI == 3) {   // gelu(tanh) == v * sigmoid(1.5957691*(v + 0.044715 v^3))
          float u = v + 0.044715f * v * v * v;
          v = v / (1.f + __expf(-1.5957691216057308f * u));
          ((uint16_t*)Cv)[cr] = f2bf(v);
        } else {
          ((uint16_t*)Cv)[cr] = f2bf(v);
        }
      }
    }
  }
}

// merged reduce + post: y<3 -> enc reduce (SK=2), y==3 -> img (SK=1, silu),
// y==4 -> post (x==0: imploss, x==1: scanfill)
__global__ __launch_bounds__(256)
void redupost_k(const float* __restrict__ Penc, const float* __restrict__ Pimg,
                const float* __restrict__ bEnc, const float* __restrict__ bImg,
                uint16_t* __restrict__ xb,
                const float* __restrict__ gate_out, float* __restrict__ out_loss,
                const int* __restrict__ counts, const int* __restrict__ topIdx,
                const float* __restrict__ topW,
                int* __restrict__ meta, int* __restrict__ perm,
                int* __restrict__ slotOf)
{
  int y = blockIdx.y, t = threadIdx.x;
  if (y < 4) {
    int row = blockIdx.x * 4 + (t >> 6);
    int c4 = (t & 63) * 4;
    bool img = (y == 3);
    const float* bias = img ? bImg : bEnc;
    f32x4 s = *(const f32x4*)&bias[c4];
    if (img) {
      s += *(const f32x4*)&Pimg[(size_t)row * 256 + c4];
      #pragma unroll
      for (int j = 0; j < 4; ++j) s[j] = s[j] / (1.f + __expf(-s[j]));
    } else {
      const float* p = Penc + (size_t)y * 2 * B_TOK * 256 + (size_t)row * 256 + c4;
      s += *(const f32x4*)p;
      s += *(const f32x4*)(p + (size_t)B_TOK * 256);
    }
    ushort4 o;
    o.x = f2bf(s[0]); o.y = f2bf(s[1]); o.z = f2bf(s[2]); o.w = f2bf(s[3]);
    *(ushort4*)&xb[(size_t)row * E_DIM + y * 256 + c4] = o;
    return;
  }
  if (blockIdx.x == 0) {                       // imploss
    float s[8] = {0.f, 0.f, 0.f, 0.f, 0.f, 0.f, 0.f, 0.f};
    for (int b = t; b < B_TOK; b += 256) {
      const float* g = &gate_out[(size_t)b * 8];
      #pragma unroll
      for (int e = 0; e < 8; ++e) s[e] += g[e];
    }
    __shared__ float red[8][256];
    #pragma unroll
    for (int e = 0; e < 8; ++e) red[e][t] = s[e];
    __syncthreads();
    for (int off = 128; off; off >>= 1) {
      if (t < off)
        #pragma unroll
        for (int e = 0; e < 8; ++e) red[e][t] += red[e][t + off];
      __syncthreads();
    }
    if (t == 0) {
      float m = 0.f;
      for (int e = 0; e < 8; e++) m += red[e][0];
      m *= 0.125f;
      float v = 0.f;
      for (int e = 0; e < 8; e++) { float d = red[e][0] - m; v += d * d; }
      v /= 7.f;                                  // ddof=1
      out_loss[0] = 0.01f * v / (m * m);
    }
  } else if (blockIdx.x == 1) {                // scanfill
    __shared__ int sBases[8];
    __shared__ int sCursor[8];
    if (t == 0) {
      int a = 0, nt = 0;
      for (int e = 0; e < 8; e++) {
        sBases[e] = a; sCursor[e] = 0;
        int c = counts[e];
        for (int j = 0; j < c; j += 128) {
          meta[1 + 3 * nt] = e;
          meta[2 + 3 * nt] = a + j;
          meta[3 + 3 * nt] = (c - j < 128) ? (c - j) : 128;
          nt++;
        }
        a += c;
      }
      meta[0] = nt;
    }
    __syncthreads();
    for (int b = t; b < B_TOK; b += 256) {
      #pragma unroll
      for (int j = 0; j < 2; j++) {
        int e = topIdx[b * 2 + j];
        int pos = atomicAdd(&sCursor[e], 1);
        int slot = sBases[e] + pos;
        perm[slot] = b;
        slotOf[b * 2 + j] = slot;
      }
    }
  }
}

// weighted top-2 mix from bf16 Yg (bias already added inside expert L2 GEMM)
__global__ __launch_bounds__(256)
void combine_k(const uint16_t* __restrict__ Yg, const int* __restrict__ slotOf,
               const float* __restrict__ topW, float* __restrict__ y)
{
  int b = blockIdx.x, t = threadIdx.x;
  int s0 = slotOf[b * 2], s1 = slotOf[b * 2 + 1];
  float w0 = topW[b * 2], w1 = topW[b * 2 + 1];
  ushort4 ua = *(const ushort4*)&Yg[(size_t)s0 * E_DIM + t * 4];
  ushort4 uc = *(const ushort4*)&Yg[(size_t)s1 * E_DIM + t * 4];
  f32x4 r;
  r[0] = bf2f(ua.x) * w0 + bf2f(uc.x) * w1;
  r[1] = bf2f(ua.y) * w0 + bf2f(uc.y) * w1;
  r[2] = bf2f(ua.z) * w0 + bf2f(uc.z) * w1;
  r[3] = bf2f(ua.w) * w0 + bf2f(uc.w) * w1;
  *(f32x4*)&y[(size_t)b * E_DIM + t * 4] = r;
}

// ---------------- host ----------------
extern "C" void kernel_launch(void* const* d_in, const int* in_sizes, int n_in,
                              void* d_out, int out_size, void* d_ws, size_t ws_size,
                              hipStream_t stream)
{
  (void)in_sizes; (void)n_in; (void)out_size;
  const float* src   = (const float*)d_in[0];
  const float* tgt   = (const float*)d_in[1];
  const float* bgr   = (const float*)d_in[2];
  const float* image = (const float*)d_in[3];
  const float* text  = (const float*)d_in[4];
  const float* W_enc = (const float*)d_in[5];
  const float* b_enc = (const float*)d_in[6];
  const float* W_img = (const float*)d_in[7];
  const float* b_img = (const float*)d_in[8];
  // d_in[9..12]: Wq,bq,Wk,bk — dead (softmax over length-1 key axis == 1)
  const float* Wv    = (const float*)d_in[13];
  const float* bv    = (const float*)d_in[14];
  const float* Wo    = (const float*)d_in[15];
  const float* bo    = (const float*)d_in[16];
  const float* Wg    = (const float*)d_in[17];
  const float* bgg   = (const float*)d_in[18];
  const float* W1    = (const float*)d_in[19];
  const float* b1    = (const float*)d_in[20];
  const float* W2    = (const float*)d_in[21];
  const float* b2    = (const float*)d_in[22];

  float* out_y    = (float*)d_out;
  float* out_gate = out_y + (size_t)B_TOK * E_DIM;
  float* out_loss = out_gate + (size_t)B_TOK * N_EXPC;

  char* p = (char*)d_ws;
  auto alloc = [&](size_t bytes) { char* r = p; p += (bytes + 255) & ~(size_t)255; return r; };
  uint16_t* WencT = (uint16_t*)alloc((size_t)256 * IMGSZ * 2);
  uint16_t* WimgT = (uint16_t*)alloc((size_t)256 * E_DIM * 2);
  uint16_t* W1T   = (uint16_t*)alloc((size_t)N_EXPC * HID * E_DIM * 2);
  uint16_t* W2T   = (uint16_t*)alloc((size_t)N_EXPC * E_DIM * HID * 2);
  float* part  = (float*)alloc((size_t)8 * E_DIM * 4);
  float* g1c   = (float*)alloc((size_t)E_DIM * 8 * 4);
  float* G3    = (float*)alloc((size_t)E_DIM * 8 * 4);
  float* gbv   = (float*)alloc(64 * 4);
  int*   topIdx = (int*)alloc(B_TOK * 2 * 4);
  float* topW   = (float*)alloc(B_TOK * 2 * 4);
  int*   slotOf = (int*)alloc(B_TOK * 2 * 4);
  int*   counts = (int*)alloc(64 * 4);
  int*   meta   = (int*)alloc((1 + 3 * (NTIL + 1)) * 4 + 64);
  int*   perm   = (int*)alloc(NSLOT * 4);
  uint16_t* xbf  = (uint16_t*)alloc((size_t)B_TOK * E_DIM * 2);
  uint16_t* Hbuf = (uint16_t*)alloc((size_t)NSLOT * HID * 2);
  // union region: enc partials (7 planes, 28 MB) then expert output Yg bf16 (16 MB)
  char* uni = alloc((size_t)7 * B_TOK * 256 * 4);
  float* Penc = (float*)uni;                               // 6 planes * 4 MB
  float* Pimg = Penc + (size_t)6 * B_TOK * 256;            // 1 plane
  uint16_t* Yg = (uint16_t*)uni;                           // reused after redupost
  if ((size_t)(p - (char*)d_ws) > ws_size) return;   // ws too small: fail visibly

  // D1: transW || matf1 || bvwo || zero-counts
  prep1_k<<<dim3(16969), 256, 0, stream>>>(W1, W2, W_enc, W_img, W1T, W2T, WencT, WimgT,
                                           Wo, Wg, g1c, bv, part, counts);
  // D2: matf2 || fused t1+gbias
  prep2_k<<<dim3(257), 256, 0, stream>>>(Wv, g1c, G3, part, bo, Wg, bgg, gbv);
  // D3: enc+img GEMMs (896 blocks, BK=64) || gate (4096 blocks) — mutually independent
  encgate_k<<<dim3(896 + B_TOK), 256, 0, stream>>>(
      src, tgt, bgr, image, WencT, WimgT, Penc, Pimg,
      text, G3, gbv, out_gate, topIdx, topW, counts);
  // D4: merged reduce + post (imploss, scanfill)
  redupost_k<<<dim3(B_TOK / 4, 5), 256, 0, stream>>>(
      Penc, Pimg, b_enc, b_img, xbf,
      out_gate, out_loss, counts, topIdx, topW, meta, perm, slotOf);

  // D5/D6: sparse top-2 expert MLPs (round-8 proven kernels); L2 emits bf16
  gemm_p<128, 3, true, HID / 128><<<dim3(NTIL * (HID / 128)), 256, 0, stream>>>(
      xbf, E_DIM, W1T, Hbuf, HID, b1, E_DIM, meta, perm, (size_t)HID * E_DIM, HID);
  gemm_p<128, 1, false, E_DIM / 128><<<dim3(NTIL * (E_DIM / 128)), 256, 0, stream>>>(
      Hbuf, HID, W2T, Yg, E_DIM, b2, HID, meta, perm, (size_t)E_DIM * HID, E_DIM);

  // D7: combine
  combine_k<<<B_TOK, 256, 0, stream>>>(Yg, slotOf, topW, out_y);
}